// Round 8
// baseline (386.601 us; speedup 1.0000x reference)
//
#include <hip/hip_runtime.h>
#include <stdint.h>

#define D_MODEL 1024
#define N_EXP   8
#define HIDDEN  2048
#define TOPK    2

#define BK    64
#define PADM  256
#define NT1   (D_MODEL / BK)   // 16
#define NT2   (HIDDEN / BK)    // 32
#define G1X   640              // 40 max m-tiles(256) x 16 n-tiles
#define G2X   640              // 80 max m-tiles(128) x 8 n-tiles

typedef short bf16x8 __attribute__((ext_vector_type(8)));
typedef float f32x4 __attribute__((ext_vector_type(4)));

__device__ __forceinline__ unsigned short f2bf(float f) {
    union { float f; unsigned u; } v; v.f = f;
    unsigned r = v.u + 0x7fffu + ((v.u >> 16) & 1u);
    return (unsigned short)(r >> 16);
}

__device__ __forceinline__ float bf2f(unsigned short u) {
    union { unsigned u; float f; } v; v.u = (unsigned)u << 16; return v.f;
}

__device__ __forceinline__ void gload_lds16(const void* g, void* l) {
    __builtin_amdgcn_global_load_lds(
        (const __attribute__((address_space(1))) void*)g,
        (__attribute__((address_space(3))) void*)l, 16, 0, 0);
}

// ---------------- fused prep: router + x->bf16  AND  weight convert/transpose ----------------
// blocks [0, nrouter): router role (4 tokens/block)
// blocks [nrouter, nrouter+12288): weight transpose role
__global__ __launch_bounds__(256) void k_prep(
    const float* __restrict__ x, const float* __restrict__ wr,
    const float* __restrict__ w1, const float* __restrict__ w3, const float* __restrict__ w2,
    unsigned short* __restrict__ xb,
    unsigned short* __restrict__ w13t, unsigned short* __restrict__ w2t,
    int* __restrict__ tok_e, float* __restrict__ tok_w,
    int* __restrict__ counts, int T, int nrouter)
{
    __shared__ unsigned short tls[64][68];
    const int bx = blockIdx.x;
    const int tid = threadIdx.x;

    if (bx < nrouter) {
        // ---- router + x convert ----
        int t = bx * 4 + (tid >> 6);
        int lane = tid & 63;
        if (t >= T) return;
        const float4* xr = (const float4*)(x + (size_t)t * D_MODEL);
        float acc[N_EXP];
#pragma unroll
        for (int e = 0; e < N_EXP; ++e) acc[e] = 0.f;
#pragma unroll
        for (int j = 0; j < 4; ++j) {
            int c = j * 64 + lane;
            float4 v = xr[c];
            ushort4 pk;
            pk.x = f2bf(v.x); pk.y = f2bf(v.y); pk.z = f2bf(v.z); pk.w = f2bf(v.w);
            *(ushort4*)(xb + (size_t)t * D_MODEL + c * 4) = pk;
            const float4* w4 = (const float4*)(wr + (size_t)c * 4 * N_EXP);
#pragma unroll
            for (int k = 0; k < 4; ++k) {
                float xv = (k == 0) ? v.x : (k == 1) ? v.y : (k == 2) ? v.z : v.w;
                float4 wa = w4[k * 2], wb = w4[k * 2 + 1];
                acc[0] += xv * wa.x; acc[1] += xv * wa.y; acc[2] += xv * wa.z; acc[3] += xv * wa.w;
                acc[4] += xv * wb.x; acc[5] += xv * wb.y; acc[6] += xv * wb.z; acc[7] += xv * wb.w;
            }
        }
#pragma unroll
        for (int off = 32; off > 0; off >>= 1) {
#pragma unroll
            for (int e = 0; e < N_EXP; ++e) acc[e] += __shfl_down(acc[e], off, 64);
        }
        if (lane == 0) {
            float mx = acc[0];
#pragma unroll
            for (int e = 1; e < N_EXP; ++e) mx = fmaxf(mx, acc[e]);
            float p[N_EXP], den = 0.f;
#pragma unroll
            for (int e = 0; e < N_EXP; ++e) { p[e] = __expf(acc[e] - mx); den += p[e]; }
            float inv = 1.f / den;
            int e0 = 0; float v0 = acc[0];
#pragma unroll
            for (int e = 1; e < N_EXP; ++e) if (acc[e] > v0) { v0 = acc[e]; e0 = e; }
            int e1 = -1; float v1 = -1e30f;
#pragma unroll
            for (int e = 0; e < N_EXP; ++e) if (e != e0 && acc[e] > v1) { v1 = acc[e]; e1 = e; }
            tok_e[2 * t] = e0;     tok_w[2 * t] = p[e0] * inv;
            tok_e[2 * t + 1] = e1; tok_w[2 * t + 1] = p[e1] * inv;
            atomicAdd(&counts[e0], 1);
            atomicAdd(&counts[e1], 1);
        }
        return;
    }

    // ---- weight convert + transpose ----
    const int b2 = bx - nrouter;
    const int z = b2 >> 9;            // 0..23
    const int inner = b2 & 511;
    const int mat = z >> 3, e = z & 7;
    const float* in; int Rr, Cc;
    if (mat == 0)      { in = w1; Rr = D_MODEL; Cc = HIDDEN; }
    else if (mat == 1) { in = w3; Rr = D_MODEL; Cc = HIDDEN; }
    else               { in = w2; Rr = HIDDEN; Cc = D_MODEL; }
    const size_t eb_in = (size_t)e * Rr * Cc;
    const int tpc = Cc >> 6;
    const int c0 = (inner % tpc) * 64, r0 = (inner / tpc) * 64;
#pragma unroll
    for (int p = 0; p < 4; ++p) {
        int li = p * 256 + tid;
        int r = li >> 4, q = li & 15;
        float4 v = *(const float4*)(in + eb_in + (size_t)(r0 + r) * Cc + c0 + q * 4);
        tls[q * 4 + 0][r] = f2bf(v.x);
        tls[q * 4 + 1][r] = f2bf(v.y);
        tls[q * 4 + 2][r] = f2bf(v.z);
        tls[q * 4 + 3][r] = f2bf(v.w);
    }
    __syncthreads();
    if (mat < 2) {
        // interleave w1/w3: h-col C -> row ((C>>4)<<5) + (mat?16:0) + (C&15)
        const size_t eb = (size_t)e * (2 * HIDDEN) * D_MODEL;
        const int moff = mat ? 16 : 0;
#pragma unroll
        for (int p = 0; p < 2; ++p) {
            int li = p * 256 + tid;
            int c = li >> 3, j = li & 7;
            int C = c0 + c;
            int r13 = ((C >> 4) << 5) + moff + (C & 15);
            bf16x8 v = *(const bf16x8*)(&tls[c][j * 8]);
            *(bf16x8*)(&w13t[eb + (size_t)r13 * D_MODEL + r0 + j * 8]) = v;
        }
    } else {
        const size_t eb = (size_t)e * D_MODEL * HIDDEN;
#pragma unroll
        for (int p = 0; p < 2; ++p) {
            int li = p * 256 + tid;
            int c = li >> 3, j = li & 7;
            bf16x8 v = *(const bf16x8*)(&tls[c][j * 8]);
            *(bf16x8*)(&w2t[eb + (size_t)(c0 + c) * HIDDEN + r0 + j * 8]) = v;
        }
    }
}

// ---------------- scan (padded to PADM) + scatter, single block ----------------
__global__ void k_scan_scatter(const int* __restrict__ counts,
                               const int* __restrict__ tok_e, const float* __restrict__ tok_w,
                               int* __restrict__ offs,
                               int* __restrict__ row_token, float* __restrict__ row_weight,
                               int* __restrict__ tok_pos, int T) {
    __shared__ int scurs[N_EXP];
    if (threadIdx.x == 0) {
        int s = 0;
        for (int e = 0; e < N_EXP; ++e) {
            offs[e] = s; scurs[e] = s;
            s += ((counts[e] + PADM - 1) / PADM) * PADM;
        }
        offs[N_EXP] = s;
    }
    __syncthreads();
    for (int i = threadIdx.x; i < 2 * T; i += blockDim.x) {
        int e = tok_e[i];
        int pos = atomicAdd(&scurs[e], 1);
        row_token[pos] = i >> 1;
        row_weight[pos] = tok_w[i];
        tok_pos[i] = pos;
    }
}

// ---------------- GEMM1: 256x256, 512 thr, counted-vmcnt double-buffer ----------------
__global__ __launch_bounds__(512, 2) void k_gemm1(
    const unsigned short* __restrict__ xb,    // [T][D] bf16
    const unsigned short* __restrict__ w13t,  // [E][2H][D] bf16 interleaved
    const int* __restrict__ row_token,
    const float* __restrict__ row_weight,
    const int* __restrict__ offs,             // [E+1] 256-padded
    unsigned short* __restrict__ h)           // [Rp][H] bf16
{
    __shared__ unsigned short A[2][256 * BK];   // 2 x 32 KB
    __shared__ unsigned short B[2][256 * BK];   // 2 x 32 KB

    const int b = blockIdx.x;
    const int bs = (b & 7) * (G1X / 8) + (b >> 3);
    int e = 0, mt = 0, nt = 0, found = 0, at = 0;
#pragma unroll
    for (int ee = 0; ee < N_EXP; ++ee) {
        int me = (offs[ee + 1] - offs[ee]) >> 8;
        int te = me * 16;
        if (!found && bs < at + te) {
            int loc = bs - at;
            nt = loc / me;
            mt = loc - nt * me;
            e = ee; found = 1;
        }
        at += te;
    }
    if (!found) return;
    const int m0 = offs[e] + mt * 256;
    const int n0b = nt * 256;

    const int tid = threadIdx.x;
    const int lane = tid & 63, wid = tid >> 6;
    const int wm = wid >> 2, wn = wid & 3;       // 2M x 4N, wave tile 128x64

    const unsigned short* asrc[4];
    unsigned aoff[4];
#pragma unroll
    for (int q = 0; q < 4; ++q) {
        int c = q * 512 + tid;
        int m = c >> 3, kc = c & 7;
        int kcs = kc ^ (m & 7);
        int tok = row_token[m0 + m];
        asrc[q] = xb + (size_t)tok * D_MODEL + kcs * 8;
        aoff[q] = (unsigned)c * 8u;
    }
    const unsigned short* bsrc[4];
    unsigned boff[4];
#pragma unroll
    for (int q = 0; q < 4; ++q) {
        int c = q * 512 + tid;
        int n = c >> 3, kc = c & 7;
        int kcs = kc ^ (n & 7);
        bsrc[q] = w13t + ((size_t)e * (2 * HIDDEN) + n0b + n) * D_MODEL + kcs * 8;
        boff[q] = (unsigned)c * 8u;
    }

    f32x4 acc[8][4];
    const f32x4 zf = {0.f, 0.f, 0.f, 0.f};
#pragma unroll
    for (int mi = 0; mi < 8; ++mi)
#pragma unroll
        for (int ni = 0; ni < 4; ++ni) acc[mi][ni] = zf;

    // prologue: stage tile 0 -> buf0 (8 loads outstanding)
#pragma unroll
    for (int q = 0; q < 4; ++q) {
        gload_lds16(asrc[q], &A[0][aoff[q]]);
        gload_lds16(bsrc[q], &B[0][boff[q]]);
    }

#define G1_STEP(CUR, KT)                                                          \
    {                                                                             \
        if ((KT) + 1 < NT1) {                                                     \
            const int ko = ((KT) + 1) * BK;                                       \
            _Pragma("unroll")                                                     \
            for (int q = 0; q < 4; ++q) {                                         \
                gload_lds16(asrc[q] + ko, &A[(CUR) ^ 1][aoff[q]]);                \
                gload_lds16(bsrc[q] + ko, &B[(CUR) ^ 1][boff[q]]);                \
            }                                                                     \
            asm volatile("s_waitcnt vmcnt(8)" ::: "memory");                      \
        } else {                                                                  \
            asm volatile("s_waitcnt vmcnt(0)" ::: "memory");                      \
        }                                                                         \
        __builtin_amdgcn_s_barrier();                                             \
        asm volatile("" ::: "memory");                                            \
        _Pragma("unroll")                                                         \
        for (int kf = 0; kf < 2; ++kf) {                                          \
            bf16x8 a[8], bf[4];                                                   \
            int ke = kf * 32 + (lane >> 4) * 8;                                   \
            _Pragma("unroll")                                                     \
            for (int mi = 0; mi < 8; ++mi) {                                      \
                int m = wm * 128 + mi * 16 + (lane & 15);                         \
                a[mi] = *(const bf16x8*)(&A[CUR][m * BK + (ke ^ ((m & 7) * 8))]); \
            }                                                                     \
            _Pragma("unroll")                                                     \
            for (int ni = 0; ni < 4; ++ni) {                                      \
                int n = wn * 64 + ni * 16 + (lane & 15);                          \
                bf[ni] = *(const bf16x8*)(&B[CUR][n * BK + (ke ^ ((n & 7) * 8))]);\
            }                                                                     \
            __builtin_amdgcn_s_setprio(1);                                        \
            _Pragma("unroll")                                                     \
            for (int mi = 0; mi < 8; ++mi)                                        \
                _Pragma("unroll")                                                 \
                for (int ni = 0; ni < 4; ++ni)                                    \
                    acc[mi][ni] = __builtin_amdgcn_mfma_f32_16x16x32_bf16(        \
                        a[mi], bf[ni], acc[mi][ni], 0, 0, 0);                     \
            __builtin_amdgcn_s_setprio(0);                                        \
        }                                                                         \
        asm volatile("" ::: "memory");                                            \
        __builtin_amdgcn_s_barrier();                                             \
    }

#pragma unroll 1
    for (int kt2 = 0; kt2 < NT1; kt2 += 2) {
        G1_STEP(0, kt2);
        G1_STEP(1, kt2 + 1);
    }
#undef G1_STEP

    // epilogue: silu(acc[.][even]) * acc[.][odd] -> h
    const int g0 = (n0b + wn * 64) >> 5;
#pragma unroll
    for (int mi = 0; mi < 8; ++mi) {
#pragma unroll
        for (int r = 0; r < 4; ++r) {
            int m = wm * 128 + mi * 16 + (lane >> 4) * 4 + r;
            float wgt = row_weight[m0 + m];
            size_t rowbase = (size_t)(m0 + m) * HIDDEN;
#pragma unroll
            for (int p = 0; p < 2; ++p) {
                float v1 = acc[mi][2 * p][r], v3 = acc[mi][2 * p + 1][r];
                float sv = v1 / (1.f + __expf(-v1));
                int hc = (g0 + p) * 16 + (lane & 15);
                h[rowbase + hc] = f2bf(sv * v3 * wgt);
            }
        }
    }
}

// ---------------- GEMM2: 128x128, 256 thr, counted-vmcnt double-buffer ----------------
__global__ __launch_bounds__(256, 2) void k_gemm2(
    const unsigned short* __restrict__ h,    // [Rp][H] bf16
    const unsigned short* __restrict__ w2t,  // [E][D][H] bf16
    const int* __restrict__ offs,
    unsigned short* __restrict__ y)          // [Rp][D] bf16
{
    __shared__ unsigned short A[2][128 * BK];   // 2 x 16 KB
    __shared__ unsigned short B[2][128 * BK];   // 2 x 16 KB

    const int b = blockIdx.x;
    const int bs = (b & 7) * (G2X / 8) + (b >> 3);
    int e = 0, mt = 0, nt = 0, found = 0, at = 0;
#pragma unroll
    for (int ee = 0; ee < N_EXP; ++ee) {
        int me = (offs[ee + 1] - offs[ee]) >> 7;
        int te = me * 8;
        if (!found && bs < at + te) {
            int loc = bs - at;
            nt = loc / me;
            mt = loc - nt * me;
            e = ee; found = 1;
        }
        at += te;
    }
    if (!found) return;
    const int m0 = offs[e] + mt * 128;
    const int n0 = nt * 128;

    const int tid = threadIdx.x;
    const int lane = tid & 63, wid = tid >> 6;
    const int wm = wid >> 1, wn = wid & 1;      // 2M x 2N, wave tile 64x64

    const unsigned short* asrc[4];
    unsigned aoff[4];
#pragma unroll
    for (int q = 0; q < 4; ++q) {
        int c = q * 256 + tid;
        int m = c >> 3, kc = c & 7;
        int kcs = kc ^ (m & 7);
        asrc[q] = h + (size_t)(m0 + m) * HIDDEN + kcs * 8;
        aoff[q] = (unsigned)c * 8u;
    }
    const unsigned short* bsrc[4];
    unsigned boff[4];
#pragma unroll
    for (int q = 0; q < 4; ++q) {
        int c = q * 256 + tid;
        int n = c >> 3, kc = c & 7;
        int kcs = kc ^ (n & 7);
        bsrc[q] = w2t + ((size_t)e * D_MODEL + n0 + n) * HIDDEN + kcs * 8;
        boff[q] = (unsigned)c * 8u;
    }

    f32x4 acc[4][4];
    const f32x4 zf = {0.f, 0.f, 0.f, 0.f};
#pragma unroll
    for (int mi = 0; mi < 4; ++mi)
#pragma unroll
        for (int ni = 0; ni < 4; ++ni) acc[mi][ni] = zf;

#pragma unroll
    for (int q = 0; q < 4; ++q) {
        gload_lds16(asrc[q], &A[0][aoff[q]]);
        gload_lds16(bsrc[q], &B[0][boff[q]]);
    }

#define G2_STEP(CUR, KT)                                                          \
    {                                                                             \
        if ((KT) + 1 < NT2) {                                                     \
            const int ko = ((KT) + 1) * BK;                                       \
            _Pragma("unroll")                                                     \
            for (int q = 0; q < 4; ++q) {                                         \
                gload_lds16(asrc[q] + ko, &A[(CUR) ^ 1][aoff[q]]);                \
                gload_lds16(bsrc[q] + ko, &B[(CUR) ^ 1][boff[q]]);                \
            }                                                                     \
            asm volatile("s_waitcnt vmcnt(8)" ::: "memory");                      \
        } else {                                                                  \
            asm volatile("s_waitcnt vmcnt(0)" ::: "memory");                      \
        }                                                                         \
        __builtin_amdgcn_s_barrier();                                             \
        asm volatile("" ::: "memory");                                            \
        _Pragma("unroll")                                                         \
        for (int kf = 0; kf < 2; ++kf) {                                          \
            bf16x8 a[4], bf[4];                                                   \
            int ke = kf * 32 + (lane >> 4) * 8;                                   \
            _Pragma("unroll")                                                     \
            for (int mi = 0; mi < 4; ++mi) {                                      \
                int m = wm * 64 + mi * 16 + (lane & 15);                          \
                a[mi] = *(const bf16x8*)(&A[CUR][m * BK + (ke ^ ((m & 7) * 8))]); \
            }                                                                     \
            _Pragma("unroll")                                                     \
            for (int ni = 0; ni < 4; ++ni) {                                      \
                int n = wn * 64 + ni * 16 + (lane & 15);                          \
                bf[ni] = *(const bf16x8*)(&B[CUR][n * BK + (ke ^ ((n & 7) * 8))]);\
            }                                                                     \
            __builtin_amdgcn_s_setprio(1);                                        \
            _Pragma("unroll")                                                     \
            for (int mi = 0; mi < 4; ++mi)                                        \
                _Pragma("unroll")                                                 \
                for (int ni = 0; ni < 4; ++ni)                                    \
                    acc[mi][ni] = __builtin_amdgcn_mfma_f32_16x16x32_bf16(        \
                        a[mi], bf[ni], acc[mi][ni], 0, 0, 0);                     \
            __builtin_amdgcn_s_setprio(0);                                        \
        }                                                                         \
        asm volatile("" ::: "memory");                                            \
        __builtin_amdgcn_s_barrier();                                             \
    }

#pragma unroll 1
    for (int kt2 = 0; kt2 < NT2; kt2 += 2) {
        G2_STEP(0, kt2);
        G2_STEP(1, kt2 + 1);
    }
#undef G2_STEP

#pragma unroll
    for (int mi = 0; mi < 4; ++mi) {
#pragma unroll
        for (int r = 0; r < 4; ++r) {
            int m = wm * 64 + mi * 16 + (lane >> 4) * 4 + r;
            size_t rowbase = (size_t)(m0 + m) * D_MODEL + n0;
#pragma unroll
            for (int ni = 0; ni < 4; ++ni) {
                int n = wn * 64 + ni * 16 + (lane & 15);
                y[rowbase + n] = f2bf(acc[mi][ni][r]);
            }
        }
    }
}

// ---------------- combine: out[t] = y[pos0] + y[pos1] ----------------
__global__ void k_combine(const unsigned short* __restrict__ y,
                          const int* __restrict__ tok_pos,
                          float* __restrict__ out, int n8) {
    int i = blockIdx.x * blockDim.x + threadIdx.x;
    if (i >= n8) return;
    int t = i >> 7;
    int c = (i & 127) * 8;
    int p0 = tok_pos[2 * t];
    int p1 = tok_pos[2 * t + 1];
    bf16x8 v0 = *(const bf16x8*)(y + (size_t)p0 * D_MODEL + c);
    bf16x8 v1 = *(const bf16x8*)(y + (size_t)p1 * D_MODEL + c);
    float* op = out + (size_t)t * D_MODEL + c;
    float4 o0, o1;
    o0.x = bf2f((unsigned short)v0[0]) + bf2f((unsigned short)v1[0]);
    o0.y = bf2f((unsigned short)v0[1]) + bf2f((unsigned short)v1[1]);
    o0.z = bf2f((unsigned short)v0[2]) + bf2f((unsigned short)v1[2]);
    o0.w = bf2f((unsigned short)v0[3]) + bf2f((unsigned short)v1[3]);
    o1.x = bf2f((unsigned short)v0[4]) + bf2f((unsigned short)v1[4]);
    o1.y = bf2f((unsigned short)v0[5]) + bf2f((unsigned short)v1[5]);
    o1.z = bf2f((unsigned short)v0[6]) + bf2f((unsigned short)v1[6]);
    o1.w = bf2f((unsigned short)v0[7]) + bf2f((unsigned short)v1[7]);
    *(float4*)op = o0;
    *(float4*)(op + 4) = o1;
}

extern "C" void kernel_launch(void* const* d_in, const int* in_sizes, int n_in,
                              void* d_out, int out_size, void* d_ws, size_t ws_size,
                              hipStream_t stream) {
    const float* x  = (const float*)d_in[0];
    const float* wr = (const float*)d_in[1];
    const float* w1 = (const float*)d_in[2];
    const float* w3 = (const float*)d_in[3];
    const float* w2 = (const float*)d_in[4];
    float* out = (float*)d_out;

    const int T = in_sizes[0] / D_MODEL;    // 4096
    const int Rp = T * TOPK + N_EXP * PADM; // 10240 padded row bound

    char* ws = (char*)d_ws;
    size_t o = 0;
    unsigned short* xb   = (unsigned short*)(ws + o); o += (size_t)T * D_MODEL * 2;
    unsigned short* h    = (unsigned short*)(ws + o); o += (size_t)Rp * HIDDEN * 2;
    unsigned short* w13t = (unsigned short*)(ws + o); o += (size_t)N_EXP * 2 * HIDDEN * D_MODEL * 2;
    unsigned short* w2t  = (unsigned short*)(ws + o); o += (size_t)N_EXP * D_MODEL * HIDDEN * 2;
    int*   row_token  = (int*)(ws + o);   o += (size_t)Rp * 4;
    float* row_weight = (float*)(ws + o); o += (size_t)Rp * 4;
    int*   tok_e      = (int*)(ws + o);   o += (size_t)2 * T * 4;
    float* tok_w      = (float*)(ws + o); o += (size_t)2 * T * 4;
    int*   tok_pos    = (int*)(ws + o);   o += (size_t)2 * T * 4;
    int*   counts     = (int*)(ws + o);   o += 16 * 4;
    int*   offs       = (int*)(ws + o);   o += 16 * 4;

    // y aliases w13t (dead after gemm1)
    unsigned short* y = w13t;

    hipMemsetAsync(counts, 0, 16 * 4, stream);
    hipMemsetAsync(row_token, 0, (size_t)Rp * 4, stream);
    hipMemsetAsync(row_weight, 0, (size_t)Rp * 4, stream);

    const int nrouter = (T + 3) / 4;            // 1024
    const int nprep = nrouter + 24 * 512;       // + 12288 transpose blocks
    k_prep<<<nprep, 256, 0, stream>>>(x, wr, w1, w3, w2, xb, w13t, w2t,
                                      tok_e, tok_w, counts, T, nrouter);

    k_scan_scatter<<<1, 1024, 0, stream>>>(counts, tok_e, tok_w, offs,
                                           row_token, row_weight, tok_pos, T);

    k_gemm1<<<G1X, 512, 0, stream>>>(xb, w13t, row_token, row_weight, offs, h);
    k_gemm2<<<G2X, 256, 0, stream>>>(h, w2t, offs, y);

    int n8 = T * D_MODEL / 8;
    k_combine<<<(n8 + 255) / 256, 256, 0, stream>>>(y, tok_pos, out, n8);
}

// Round 9
// 329.173 us; speedup vs baseline: 1.1745x; 1.1745x over previous
//
#include <hip/hip_runtime.h>
#include <stdint.h>

#define D_MODEL 1024
#define N_EXP   8
#define HIDDEN  2048
#define TOPK    2

#define BK    64
#define PADM  128
#define NT1   (D_MODEL / BK)   // 16
#define NT2   (HIDDEN / BK)    // 32
#define G1X   1152             // 72 max m-tiles(128) x 16 n-tiles(256 of 2H)
#define G2X   288              // 72 max m-tiles(128) x 4 n-tiles(256 of D)

typedef short bf16x8 __attribute__((ext_vector_type(8)));
typedef float f32x4 __attribute__((ext_vector_type(4)));

__device__ __forceinline__ unsigned short f2bf(float f) {
    union { float f; unsigned u; } v; v.f = f;
    unsigned r = v.u + 0x7fffu + ((v.u >> 16) & 1u);
    return (unsigned short)(r >> 16);
}

__device__ __forceinline__ float bf2f(unsigned short u) {
    union { unsigned u; float f; } v; v.u = (unsigned)u << 16; return v.f;
}

__device__ __forceinline__ void gload_lds16(const void* g, void* l) {
    __builtin_amdgcn_global_load_lds(
        (const __attribute__((address_space(1))) void*)g,
        (__attribute__((address_space(3))) void*)l, 16, 0, 0);
}

// ---------------- fused prep: router + x->bf16  AND  weight convert/transpose ----------------
__global__ __launch_bounds__(256) void k_prep(
    const float* __restrict__ x, const float* __restrict__ wr,
    const float* __restrict__ w1, const float* __restrict__ w3, const float* __restrict__ w2,
    unsigned short* __restrict__ xb,
    unsigned short* __restrict__ w13t, unsigned short* __restrict__ w2t,
    int* __restrict__ tok_e, float* __restrict__ tok_w,
    int* __restrict__ counts, int T, int nrouter)
{
    __shared__ unsigned short tls[64][68];
    const int bx = blockIdx.x;
    const int tid = threadIdx.x;

    if (bx < nrouter) {
        int t = bx * 4 + (tid >> 6);
        int lane = tid & 63;
        if (t >= T) return;
        const float4* xr = (const float4*)(x + (size_t)t * D_MODEL);
        float acc[N_EXP];
#pragma unroll
        for (int e = 0; e < N_EXP; ++e) acc[e] = 0.f;
#pragma unroll
        for (int j = 0; j < 4; ++j) {
            int c = j * 64 + lane;
            float4 v = xr[c];
            ushort4 pk;
            pk.x = f2bf(v.x); pk.y = f2bf(v.y); pk.z = f2bf(v.z); pk.w = f2bf(v.w);
            *(ushort4*)(xb + (size_t)t * D_MODEL + c * 4) = pk;
            const float4* w4 = (const float4*)(wr + (size_t)c * 4 * N_EXP);
#pragma unroll
            for (int k = 0; k < 4; ++k) {
                float xv = (k == 0) ? v.x : (k == 1) ? v.y : (k == 2) ? v.z : v.w;
                float4 wa = w4[k * 2], wb = w4[k * 2 + 1];
                acc[0] += xv * wa.x; acc[1] += xv * wa.y; acc[2] += xv * wa.z; acc[3] += xv * wa.w;
                acc[4] += xv * wb.x; acc[5] += xv * wb.y; acc[6] += xv * wb.z; acc[7] += xv * wb.w;
            }
        }
#pragma unroll
        for (int off = 32; off > 0; off >>= 1) {
#pragma unroll
            for (int e = 0; e < N_EXP; ++e) acc[e] += __shfl_down(acc[e], off, 64);
        }
        if (lane == 0) {
            float mx = acc[0];
#pragma unroll
            for (int e = 1; e < N_EXP; ++e) mx = fmaxf(mx, acc[e]);
            float p[N_EXP], den = 0.f;
#pragma unroll
            for (int e = 0; e < N_EXP; ++e) { p[e] = __expf(acc[e] - mx); den += p[e]; }
            float inv = 1.f / den;
            int e0 = 0; float v0 = acc[0];
#pragma unroll
            for (int e = 1; e < N_EXP; ++e) if (acc[e] > v0) { v0 = acc[e]; e0 = e; }
            int e1 = -1; float v1 = -1e30f;
#pragma unroll
            for (int e = 0; e < N_EXP; ++e) if (e != e0 && acc[e] > v1) { v1 = acc[e]; e1 = e; }
            tok_e[2 * t] = e0;     tok_w[2 * t] = p[e0] * inv;
            tok_e[2 * t + 1] = e1; tok_w[2 * t + 1] = p[e1] * inv;
            atomicAdd(&counts[e0], 1);
            atomicAdd(&counts[e1], 1);
        }
        return;
    }

    const int b2 = bx - nrouter;
    const int z = b2 >> 9;
    const int inner = b2 & 511;
    const int mat = z >> 3, e = z & 7;
    const float* in; int Rr, Cc;
    if (mat == 0)      { in = w1; Rr = D_MODEL; Cc = HIDDEN; }
    else if (mat == 1) { in = w3; Rr = D_MODEL; Cc = HIDDEN; }
    else               { in = w2; Rr = HIDDEN; Cc = D_MODEL; }
    const size_t eb_in = (size_t)e * Rr * Cc;
    const int tpc = Cc >> 6;
    const int c0 = (inner % tpc) * 64, r0 = (inner / tpc) * 64;
#pragma unroll
    for (int p = 0; p < 4; ++p) {
        int li = p * 256 + tid;
        int r = li >> 4, q = li & 15;
        float4 v = *(const float4*)(in + eb_in + (size_t)(r0 + r) * Cc + c0 + q * 4);
        tls[q * 4 + 0][r] = f2bf(v.x);
        tls[q * 4 + 1][r] = f2bf(v.y);
        tls[q * 4 + 2][r] = f2bf(v.z);
        tls[q * 4 + 3][r] = f2bf(v.w);
    }
    __syncthreads();
    if (mat < 2) {
        const size_t eb = (size_t)e * (2 * HIDDEN) * D_MODEL;
        const int moff = mat ? 16 : 0;
#pragma unroll
        for (int p = 0; p < 2; ++p) {
            int li = p * 256 + tid;
            int c = li >> 3, j = li & 7;
            int C = c0 + c;
            int r13 = ((C >> 4) << 5) + moff + (C & 15);
            bf16x8 v = *(const bf16x8*)(&tls[c][j * 8]);
            *(bf16x8*)(&w13t[eb + (size_t)r13 * D_MODEL + r0 + j * 8]) = v;
        }
    } else {
        const size_t eb = (size_t)e * D_MODEL * HIDDEN;
#pragma unroll
        for (int p = 0; p < 2; ++p) {
            int li = p * 256 + tid;
            int c = li >> 3, j = li & 7;
            bf16x8 v = *(const bf16x8*)(&tls[c][j * 8]);
            *(bf16x8*)(&w2t[eb + (size_t)(c0 + c) * HIDDEN + r0 + j * 8]) = v;
        }
    }
}

// ---------------- scan (padded to PADM) + scatter, single block ----------------
__global__ void k_scan_scatter(const int* __restrict__ counts,
                               const int* __restrict__ tok_e, const float* __restrict__ tok_w,
                               int* __restrict__ offs,
                               int* __restrict__ row_token, float* __restrict__ row_weight,
                               int* __restrict__ tok_pos, int T) {
    __shared__ int scurs[N_EXP];
    if (threadIdx.x == 0) {
        int s = 0;
        for (int e = 0; e < N_EXP; ++e) {
            offs[e] = s; scurs[e] = s;
            s += ((counts[e] + PADM - 1) / PADM) * PADM;
        }
        offs[N_EXP] = s;
    }
    __syncthreads();
    for (int i = threadIdx.x; i < 2 * T; i += blockDim.x) {
        int e = tok_e[i];
        int pos = atomicAdd(&scurs[e], 1);
        row_token[pos] = i >> 1;
        row_weight[pos] = tok_w[i];
        tok_pos[i] = pos;
    }
}

// ---------------- GEMM1: 128x256, 3-buf distance-2 counted-vmcnt pipeline ----------------
__global__ __launch_bounds__(512, 1) void k_gemm1(
    const unsigned short* __restrict__ xb,    // [T][D] bf16
    const unsigned short* __restrict__ w13t,  // [E][2H][D] bf16 interleaved
    const int* __restrict__ row_token,
    const float* __restrict__ row_weight,
    const int* __restrict__ offs,             // [E+1] 128-padded
    unsigned short* __restrict__ h)           // [Rp][H] bf16
{
    __shared__ unsigned short A[3][128 * BK];   // 3 x 16 KB
    __shared__ unsigned short B[3][256 * BK];   // 3 x 32 KB

    const int b = blockIdx.x;
    const int bs = (b & 7) * (G1X / 8) + (b >> 3);
    int e = 0, mt = 0, nt = 0, found = 0, at = 0;
#pragma unroll
    for (int ee = 0; ee < N_EXP; ++ee) {
        int me = (offs[ee + 1] - offs[ee]) >> 7;
        int te = me * 16;
        if (!found && bs < at + te) {
            int loc = bs - at;
            nt = loc / me;
            mt = loc - nt * me;
            e = ee; found = 1;
        }
        at += te;
    }
    if (!found) return;
    const int m0 = offs[e] + mt * 128;
    const int n0b = nt * 256;

    const int tid = threadIdx.x;
    const int lane = tid & 63, wid = tid >> 6;
    const int wm = wid >> 2, wn = wid & 3;     // 2M x 4N, wave tile 64x64

    // A staging: 2 loads/thread/K-tile
    const unsigned short* asrc[2];
    unsigned aoff[2];
#pragma unroll
    for (int q = 0; q < 2; ++q) {
        int c = q * 512 + tid;
        int m = c >> 3, kc = c & 7;
        int kcs = kc ^ (m & 7);
        int tok = row_token[m0 + m];
        asrc[q] = xb + (size_t)tok * D_MODEL + kcs * 8;
        aoff[q] = (unsigned)c * 8u;
    }
    // B staging: 4 loads/thread/K-tile
    const unsigned short* bsrc[4];
    unsigned boff[4];
#pragma unroll
    for (int q = 0; q < 4; ++q) {
        int c = q * 512 + tid;
        int n = c >> 3, kc = c & 7;
        int kcs = kc ^ (n & 7);
        bsrc[q] = w13t + ((size_t)e * (2 * HIDDEN) + n0b + n) * D_MODEL + kcs * 8;
        boff[q] = (unsigned)c * 8u;
    }

    f32x4 acc[4][4];
    const f32x4 zf = {0.f, 0.f, 0.f, 0.f};
#pragma unroll
    for (int mi = 0; mi < 4; ++mi)
#pragma unroll
        for (int ni = 0; ni < 4; ++ni) acc[mi][ni] = zf;

    // prologue: stage tiles 0,1 -> bufs 0,1 (12 loads outstanding)
#pragma unroll
    for (int t = 0; t < 2; ++t) {
        const int ko = t * BK;
        gload_lds16(asrc[0] + ko, &A[t][aoff[0]]);
        gload_lds16(asrc[1] + ko, &A[t][aoff[1]]);
        gload_lds16(bsrc[0] + ko, &B[t][boff[0]]);
        gload_lds16(bsrc[1] + ko, &B[t][boff[1]]);
        gload_lds16(bsrc[2] + ko, &B[t][boff[2]]);
        gload_lds16(bsrc[3] + ko, &B[t][boff[3]]);
    }

    int cur = 0;
#pragma unroll 1
    for (int kt = 0; kt < NT1; ++kt) {
        // boundary: tile kt's loads are >= 2 K-tiles old; leave newest 6 (kt+1) in flight
        if (kt == NT1 - 1) asm volatile("s_waitcnt vmcnt(0)" ::: "memory");
        else               asm volatile("s_waitcnt vmcnt(6)" ::: "memory");
        __builtin_amdgcn_s_barrier();

        unsigned short* Ac = &A[cur][0];
        unsigned short* Bc = &B[cur][0];
        const int nb = (cur + 2 >= 3) ? (cur - 1) : (cur + 2);
        const int ko = (kt + 2) * BK;
        const bool pf = (kt + 2 < NT1);

        // phase 0: kf = 0
        {
            bf16x8 a0[4], b0[4];
            int ke = (lane >> 4) * 8;
#pragma unroll
            for (int mi = 0; mi < 4; ++mi) {
                int m = wm * 64 + mi * 16 + (lane & 15);
                a0[mi] = *(const bf16x8*)(&Ac[m * BK + (ke ^ ((m & 7) * 8))]);
            }
#pragma unroll
            for (int ni = 0; ni < 4; ++ni) {
                int n = wn * 64 + ni * 16 + (lane & 15);
                b0[ni] = *(const bf16x8*)(&Bc[n * BK + (ke ^ ((n & 7) * 8))]);
            }
            if (pf) {
                gload_lds16(asrc[0] + ko, &A[nb][aoff[0]]);
                gload_lds16(asrc[1] + ko, &A[nb][aoff[1]]);
                gload_lds16(bsrc[0] + ko, &B[nb][boff[0]]);
            }
            __builtin_amdgcn_s_barrier();
            __builtin_amdgcn_s_setprio(1);
#pragma unroll
            for (int mi = 0; mi < 4; ++mi)
#pragma unroll
                for (int ni = 0; ni < 4; ++ni)
                    acc[mi][ni] = __builtin_amdgcn_mfma_f32_16x16x32_bf16(a0[mi], b0[ni], acc[mi][ni], 0, 0, 0);
            __builtin_amdgcn_s_setprio(0);
        }
        // phase 1: kf = 1
        {
            bf16x8 a1[4], b1[4];
            int ke = 32 + (lane >> 4) * 8;
#pragma unroll
            for (int mi = 0; mi < 4; ++mi) {
                int m = wm * 64 + mi * 16 + (lane & 15);
                a1[mi] = *(const bf16x8*)(&Ac[m * BK + (ke ^ ((m & 7) * 8))]);
            }
#pragma unroll
            for (int ni = 0; ni < 4; ++ni) {
                int n = wn * 64 + ni * 16 + (lane & 15);
                b1[ni] = *(const bf16x8*)(&Bc[n * BK + (ke ^ ((n & 7) * 8))]);
            }
            if (pf) {
                gload_lds16(bsrc[1] + ko, &B[nb][boff[1]]);
                gload_lds16(bsrc[2] + ko, &B[nb][boff[2]]);
                gload_lds16(bsrc[3] + ko, &B[nb][boff[3]]);
            }
            __builtin_amdgcn_s_barrier();
            __builtin_amdgcn_s_setprio(1);
#pragma unroll
            for (int mi = 0; mi < 4; ++mi)
#pragma unroll
                for (int ni = 0; ni < 4; ++ni)
                    acc[mi][ni] = __builtin_amdgcn_mfma_f32_16x16x32_bf16(a1[mi], b1[ni], acc[mi][ni], 0, 0, 0);
            __builtin_amdgcn_s_setprio(0);
        }
        cur = (cur == 2) ? 0 : (cur + 1);
    }

    // epilogue: silu(acc[.][even]) * acc[.][odd] -> h
    const int g0 = (n0b + wn * 64) >> 5;
#pragma unroll
    for (int mi = 0; mi < 4; ++mi) {
#pragma unroll
        for (int r = 0; r < 4; ++r) {
            int m = wm * 64 + mi * 16 + (lane >> 4) * 4 + r;
            float wgt = row_weight[m0 + m];
            size_t rowbase = (size_t)(m0 + m) * HIDDEN;
#pragma unroll
            for (int p = 0; p < 2; ++p) {
                float v1 = acc[mi][2 * p][r], v3 = acc[mi][2 * p + 1][r];
                float sv = v1 / (1.f + __expf(-v1));
                int hc = (g0 + p) * 16 + (lane & 15);
                h[rowbase + hc] = f2bf(sv * v3 * wgt);
            }
        }
    }
}

// ---------------- GEMM2: 128x256, 3-buf distance-2 counted-vmcnt pipeline ----------------
__global__ __launch_bounds__(512, 1) void k_gemm2(
    const unsigned short* __restrict__ h,    // [Rp][H] bf16
    const unsigned short* __restrict__ w2t,  // [E][D][H] bf16
    const int* __restrict__ offs,
    unsigned short* __restrict__ y)          // [Rp][D] bf16
{
    __shared__ unsigned short A[3][128 * BK];   // 3 x 16 KB
    __shared__ unsigned short B[3][256 * BK];   // 3 x 32 KB

    const int b = blockIdx.x;
    const int bs = (b & 7) * (G2X / 8) + (b >> 3);
    int e = 0, mt = 0, nt = 0, found = 0, at = 0;
#pragma unroll
    for (int ee = 0; ee < N_EXP; ++ee) {
        int me = (offs[ee + 1] - offs[ee]) >> 7;
        int te = me * 4;
        if (!found && bs < at + te) {
            int loc = bs - at;
            nt = loc / me;
            mt = loc - nt * me;
            e = ee; found = 1;
        }
        at += te;
    }
    if (!found) return;
    const int m0 = offs[e] + mt * 128;
    const int n0 = nt * 256;

    const int tid = threadIdx.x;
    const int lane = tid & 63, wid = tid >> 6;
    const int wm = wid >> 2, wn = wid & 3;

    const unsigned short* asrc[2];
    unsigned aoff[2];
#pragma unroll
    for (int q = 0; q < 2; ++q) {
        int c = q * 512 + tid;
        int m = c >> 3, kc = c & 7;
        int kcs = kc ^ (m & 7);
        asrc[q] = h + (size_t)(m0 + m) * HIDDEN + kcs * 8;
        aoff[q] = (unsigned)c * 8u;
    }
    const unsigned short* bsrc[4];
    unsigned boff[4];
#pragma unroll
    for (int q = 0; q < 4; ++q) {
        int c = q * 512 + tid;
        int n = c >> 3, kc = c & 7;
        int kcs = kc ^ (n & 7);
        bsrc[q] = w2t + ((size_t)e * D_MODEL + n0 + n) * HIDDEN + kcs * 8;
        boff[q] = (unsigned)c * 8u;
    }

    f32x4 acc[4][4];
    const f32x4 zf = {0.f, 0.f, 0.f, 0.f};
#pragma unroll
    for (int mi = 0; mi < 4; ++mi)
#pragma unroll
        for (int ni = 0; ni < 4; ++ni) acc[mi][ni] = zf;

#pragma unroll
    for (int t = 0; t < 2; ++t) {
        const int ko = t * BK;
        gload_lds16(asrc[0] + ko, &A[t][aoff[0]]);
        gload_lds16(asrc[1] + ko, &A[t][aoff[1]]);
        gload_lds16(bsrc[0] + ko, &B[t][boff[0]]);
        gload_lds16(bsrc[1] + ko, &B[t][boff[1]]);
        gload_lds16(bsrc[2] + ko, &B[t][boff[2]]);
        gload_lds16(bsrc[3] + ko, &B[t][boff[3]]);
    }

    int cur = 0;
#pragma unroll 1
    for (int kt = 0; kt < NT2; ++kt) {
        if (kt == NT2 - 1) asm volatile("s_waitcnt vmcnt(0)" ::: "memory");
        else               asm volatile("s_waitcnt vmcnt(6)" ::: "memory");
        __builtin_amdgcn_s_barrier();

        unsigned short* Ac = &A[cur][0];
        unsigned short* Bc = &B[cur][0];
        const int nb = (cur + 2 >= 3) ? (cur - 1) : (cur + 2);
        const int ko = (kt + 2) * BK;
        const bool pf = (kt + 2 < NT2);

        // phase 0: kf = 0
        {
            bf16x8 a0[4], b0[4];
            int ke = (lane >> 4) * 8;
#pragma unroll
            for (int mi = 0; mi < 4; ++mi) {
                int m = wm * 64 + mi * 16 + (lane & 15);
                a0[mi] = *(const bf16x8*)(&Ac[m * BK + (ke ^ ((m & 7) * 8))]);
            }
#pragma unroll
            for (int ni = 0; ni < 4; ++ni) {
                int n = wn * 64 + ni * 16 + (lane & 15);
                b0[ni] = *(const bf16x8*)(&Bc[n * BK + (ke ^ ((n & 7) * 8))]);
            }
            if (pf) {
                gload_lds16(asrc[0] + ko, &A[nb][aoff[0]]);
                gload_lds16(asrc[1] + ko, &A[nb][aoff[1]]);
                gload_lds16(bsrc[0] + ko, &B[nb][boff[0]]);
            }
            __builtin_amdgcn_s_barrier();
            __builtin_amdgcn_s_setprio(1);
#pragma unroll
            for (int mi = 0; mi < 4; ++mi)
#pragma unroll
                for (int ni = 0; ni < 4; ++ni)
                    acc[mi][ni] = __builtin_amdgcn_mfma_f32_16x16x32_bf16(a0[mi], b0[ni], acc[mi][ni], 0, 0, 0);
            __builtin_amdgcn_s_setprio(0);
        }
        // phase 1: kf = 1
        {
            bf16x8 a1[4], b1[4];
            int ke = 32 + (lane >> 4) * 8;
#pragma unroll
            for (int mi = 0; mi < 4; ++mi) {
                int m = wm * 64 + mi * 16 + (lane & 15);
                a1[mi] = *(const bf16x8*)(&Ac[m * BK + (ke ^ ((m & 7) * 8))]);
            }
#pragma unroll
            for (int ni = 0; ni < 4; ++ni) {
                int n = wn * 64 + ni * 16 + (lane & 15);
                b1[ni] = *(const bf16x8*)(&Bc[n * BK + (ke ^ ((n & 7) * 8))]);
            }
            if (pf) {
                gload_lds16(bsrc[1] + ko, &B[nb][boff[1]]);
                gload_lds16(bsrc[2] + ko, &B[nb][boff[2]]);
                gload_lds16(bsrc[3] + ko, &B[nb][boff[3]]);
            }
            __builtin_amdgcn_s_barrier();
            __builtin_amdgcn_s_setprio(1);
#pragma unroll
            for (int mi = 0; mi < 4; ++mi)
#pragma unroll
                for (int ni = 0; ni < 4; ++ni)
                    acc[mi][ni] = __builtin_amdgcn_mfma_f32_16x16x32_bf16(a1[mi], b1[ni], acc[mi][ni], 0, 0, 0);
            __builtin_amdgcn_s_setprio(0);
        }
        cur = (cur == 2) ? 0 : (cur + 1);
    }

#pragma unroll
    for (int mi = 0; mi < 4; ++mi) {
#pragma unroll
        for (int r = 0; r < 4; ++r) {
            int m = wm * 64 + mi * 16 + (lane >> 4) * 4 + r;
            size_t rowbase = (size_t)(m0 + m) * D_MODEL + n0;
#pragma unroll
            for (int ni = 0; ni < 4; ++ni) {
                int n = wn * 64 + ni * 16 + (lane & 15);
                y[rowbase + n] = f2bf(acc[mi][ni][r]);
            }
        }
    }
}

// ---------------- combine: out[t] = y[pos0] + y[pos1] ----------------
__global__ void k_combine(const unsigned short* __restrict__ y,
                          const int* __restrict__ tok_pos,
                          float* __restrict__ out, int n8) {
    int i = blockIdx.x * blockDim.x + threadIdx.x;
    if (i >= n8) return;
    int t = i >> 7;
    int c = (i & 127) * 8;
    int p0 = tok_pos[2 * t];
    int p1 = tok_pos[2 * t + 1];
    bf16x8 v0 = *(const bf16x8*)(y + (size_t)p0 * D_MODEL + c);
    bf16x8 v1 = *(const bf16x8*)(y + (size_t)p1 * D_MODEL + c);
    float* op = out + (size_t)t * D_MODEL + c;
    float4 o0, o1;
    o0.x = bf2f((unsigned short)v0[0]) + bf2f((unsigned short)v1[0]);
    o0.y = bf2f((unsigned short)v0[1]) + bf2f((unsigned short)v1[1]);
    o0.z = bf2f((unsigned short)v0[2]) + bf2f((unsigned short)v1[2]);
    o0.w = bf2f((unsigned short)v0[3]) + bf2f((unsigned short)v1[3]);
    o1.x = bf2f((unsigned short)v0[4]) + bf2f((unsigned short)v1[4]);
    o1.y = bf2f((unsigned short)v0[5]) + bf2f((unsigned short)v1[5]);
    o1.z = bf2f((unsigned short)v0[6]) + bf2f((unsigned short)v1[6]);
    o1.w = bf2f((unsigned short)v0[7]) + bf2f((unsigned short)v1[7]);
    *(float4*)op = o0;
    *(float4*)(op + 4) = o1;
}

extern "C" void kernel_launch(void* const* d_in, const int* in_sizes, int n_in,
                              void* d_out, int out_size, void* d_ws, size_t ws_size,
                              hipStream_t stream) {
    const float* x  = (const float*)d_in[0];
    const float* wr = (const float*)d_in[1];
    const float* w1 = (const float*)d_in[2];
    const float* w3 = (const float*)d_in[3];
    const float* w2 = (const float*)d_in[4];
    float* out = (float*)d_out;

    const int T = in_sizes[0] / D_MODEL;    // 4096
    const int Rp = T * TOPK + N_EXP * PADM; // 9216 padded row bound

    char* ws = (char*)d_ws;
    size_t o = 0;
    unsigned short* xb   = (unsigned short*)(ws + o); o += (size_t)T * D_MODEL * 2;
    unsigned short* h    = (unsigned short*)(ws + o); o += (size_t)Rp * HIDDEN * 2;
    unsigned short* w13t = (unsigned short*)(ws + o); o += (size_t)N_EXP * 2 * HIDDEN * D_MODEL * 2;
    unsigned short* w2t  = (unsigned short*)(ws + o); o += (size_t)N_EXP * D_MODEL * HIDDEN * 2;
    int*   row_token  = (int*)(ws + o);   o += (size_t)Rp * 4;
    float* row_weight = (float*)(ws + o); o += (size_t)Rp * 4;
    int*   tok_e      = (int*)(ws + o);   o += (size_t)2 * T * 4;
    float* tok_w      = (float*)(ws + o); o += (size_t)2 * T * 4;
    int*   tok_pos    = (int*)(ws + o);   o += (size_t)2 * T * 4;
    int*   counts     = (int*)(ws + o);   o += 16 * 4;
    int*   offs       = (int*)(ws + o);   o += 16 * 4;

    // y aliases w13t (dead after gemm1)
    unsigned short* y = w13t;

    hipMemsetAsync(counts, 0, 16 * 4, stream);
    hipMemsetAsync(row_token, 0, (size_t)Rp * 4, stream);
    hipMemsetAsync(row_weight, 0, (size_t)Rp * 4, stream);

    const int nrouter = (T + 3) / 4;            // 1024
    const int nprep = nrouter + 24 * 512;       // + 12288 transpose blocks
    k_prep<<<nprep, 256, 0, stream>>>(x, wr, w1, w3, w2, xb, w13t, w2t,
                                      tok_e, tok_w, counts, T, nrouter);

    k_scan_scatter<<<1, 1024, 0, stream>>>(counts, tok_e, tok_w, offs,
                                           row_token, row_weight, tok_pos, T);

    k_gemm1<<<G1X, 512, 0, stream>>>(xb, w13t, row_token, row_weight, offs, h);
    k_gemm2<<<G2X, 512, 0, stream>>>(h, w2t, offs, y);

    int n8 = T * D_MODEL / 8;
    k_combine<<<(n8 + 255) / 256, 256, 0, stream>>>(y, tok_pos, out, n8);
}